// Round 11
// baseline (175.815 us; speedup 1.0000x reference)
//
#include <hip/hip_runtime.h>

#define S_LEN 2048

typedef float f32x4 __attribute__((ext_vector_type(4)));
typedef int   i32x4 __attribute__((ext_vector_type(4)));
typedef int   i32x2 __attribute__((ext_vector_type(2)));

__device__ __forceinline__ float cos2pi(float rev){ float r; asm("v_cos_f32 %0, %1":"=v"(r):"v"(rev)); return r; }
__device__ __forceinline__ float fractf_(float x){ float r; asm("v_fract_f32 %0, %1":"=v"(r):"v"(x)); return r; }
template<int M>
__device__ __forceinline__ float swz(float x){
  return __int_as_float(__builtin_amdgcn_ds_swizzle(__float_as_int(x), M));
}
template<int CTRL>
__device__ __forceinline__ float dppmov(float x){
  return __int_as_float(__builtin_amdgcn_update_dpp(0, __float_as_int(x), CTRL, 0xf, 0xf, false));
}

// lane layout (scan): comp = l>>5 (0:h_r, 1:h_i), d = ((l>>2)&7) | ((l&3)<<3) => head(d) = l&3
// K-permutation: comb element k'' = l  <->  concat index comp*32 + d. W columns permuted identically.

// ================= scan (blocks 0..1023) + W-split prep (blocks 1024..2047) =================
// 64 chunks x 32 steps, 128-step warm-up (validated WU; R8 proved 96 insufficient).
// Body/numerics bit-identical to R9 (168.8 µs, absmax 0.0127). 3-stage pipeline:
//   AF(j) theta->rev, issue shfl | G2(j-2) | G0(j-1) folds, issue swizzle | AB(j) | G1(j-1)
__global__ __launch_bounds__(64) void scan_kernel(
    const int* __restrict__ ids, const float* __restrict__ emb,
    const float* __restrict__ Wg, const float* __restrict__ bg,
    const float* __restrict__ dlg, const float* __restrict__ esc,
    ushort* __restrict__ chi, ushort* __restrict__ clo,
    const float* __restrict__ W32, ushort* __restrict__ whi, ushort* __restrict__ wlo)
{
  const int w = blockIdx.x;
  const int l = threadIdx.x;

  if (w >= 1024){
    // ---- W_out -> bf16 hi/lo split with k'' lane permutation (validated R7/R9) ----
    int i0 = (w - 1024) * 256 + l * 4;
    int v  = i0 >> 6;
    int q  = (i0 & 63) >> 2;
    int base = v*64 + (q >> 3)*32 + (q & 7);
    float x0 = W32[base], x1 = W32[base+8], x2 = W32[base+16], x3 = W32[base+24];
    unsigned hw01, hw23, lw01, lw23;
    asm("v_cvt_pk_bf16_f32 %0, %1, %2":"=v"(hw01):"v"(x0),"v"(x1));
    asm("v_cvt_pk_bf16_f32 %0, %1, %2":"=v"(hw23):"v"(x2),"v"(x3));
    float r0 = x0 - __uint_as_float(hw01 << 16);
    float r1 = x1 - __uint_as_float(hw01 & 0xffff0000u);
    float r2 = x2 - __uint_as_float(hw23 << 16);
    float r3 = x3 - __uint_as_float(hw23 & 0xffff0000u);
    asm("v_cvt_pk_bf16_f32 %0, %1, %2":"=v"(lw01):"v"(r0),"v"(r1));
    asm("v_cvt_pk_bf16_f32 %0, %1, %2":"=v"(lw23):"v"(r2),"v"(r3));
    *(i32x2*)(whi + i0) = (i32x2){(int)hw01, (int)hw23};
    *(i32x2*)(wlo + i0) = (i32x2){(int)lw01, (int)lw23};
    return;
  }

  const int c  = w >> 4;            // chunk 0..63
  const int b  = w & 15;            // batch
  const bool lo = (l < 32);
  const int d  = ((l >> 2) & 7) | ((l & 3) << 3);
  const bool b0 = (l & 1) != 0;
  const bool b1 = (l & 2) != 0;
  const float qoff = lo ? 0.f : 0.25f;   // cos(x - 1/4 rev) = sin(x)

  const float es  = esc[0];
  const int hd = l & 3;
  const float dk  = 1.f/(1.f + __expf(-dlg[hd]));
  const float bgl = bg[hd];
  const int crow = (lo ? 0 : 32) + d;
  const f32x4 wg = *(const f32x4*)(Wg + crow*4);

  const int s0   = c*32;
  const int sw   = (s0 >= 128) ? (s0 - 128) : 0;
  const int send = s0 + 32;
  const int nq   = (send - sw) >> 2;   // 8..40 four-step groups

  const int* idb = ids + b*S_LEN;
  ushort* pch = chi + (size_t)b*S_LEN*64 + l;
  ushort* pcl = clo + (size_t)b*S_LEN*64 + l;

  const float PHI_F   = 1.6180339887498949f;
  const float TWOPI_F = 6.283185307179586f;
  const float INV2PI  = 0.15915494309189535f;

  float h = 0.f, m = 0.f;
  float h1 = 0.f, h2 = 0.f;     // h(j-1), h(j-2)
  float rev_c, rev_s;           // A pipeline (step j)
  float q0p, swp;               // G0 -> G1 (step j-1)
  float mm1p, psp;              // G1 -> G2 (step j-2)
  float w_[4], b_[4], nw_[4], nb_[4];

  auto clampi = [](int x){ return x > (S_LEN-4) ? (S_LEN-4) : x; };

  auto AF = [&](int s, float wv, float bpv){
    float invw = __builtin_amdgcn_rcpf(1.f + __builtin_fabsf(wv));
    float tp = (float)s * PHI_F;
    float th = __builtin_fmaf(h, invw, bpv) + tp;   // R3-exact order
    float qf = __builtin_floorf(th * INV2PI);
    float r  = __builtin_fmaf(-qf, TWOPI_F, th);
    r = (r < 0.f) ? (r + TWOPI_F) : r;
    r = (r >= TWOPI_F) ? (r - TWOPI_F) : r;
    rev_c = r * INV2PI;                              // [0,1)
    rev_s = __shfl_xor(rev_c, 32, 64);               // issue ds op; consume in AB
  };
  auto AB = [&](){
    float rsum = rev_c + rev_s;                      // identical rounding both halves
    float hn = cos2pi(fractf_(rsum - qoff));         // h_r=cos, h_i=sin via -1/4 rev
    h2 = h1; h1 = hn; h = hn;
  };
  auto G0 = [&](){
    float p0 = h1*wg[0], p1 = h1*wg[1], p2 = h1*wg[2], p3 = h1*wg[3];
    float m01 = b0 ? p1 : p0;
    float t01 = b0 ? p0 : p1;
    m01 += dppmov<0xB1>(t01);              // quad_perm xor1
    float m23 = b0 ? p3 : p2;
    float t23 = b0 ? p2 : p3;
    m23 += dppmov<0xB1>(t23);
    float mm = b1 ? m23 : m01;
    float tt = b1 ? m01 : m23;
    mm += dppmov<0x4E>(tt);                // quad_perm xor2
    mm += dppmov<0x124>(mm);               // row_ror:4
    mm += dppmov<0x128>(mm);               // row_ror:8
    q0p = mm;
    swp = swz<0x401F>(mm);                 // issue ds op; consume in G1
  };
  auto G1 = [&](){
    float mm1 = q0p + swp;
    mm1p = mm1;
    psp = __shfl_xor(mm1, 32, 64);         // issue ds op; consume next body's G2
  };
  auto G2 = [&](int jm2){
    float mm = mm1p + psp;                 // full 64-lane sum, all lanes
    float g_ = 1.f / (1.f + __expf(-(mm + bgl)));
    m = __builtin_fmaf(dk, m, g_*h2);
    float outv = __builtin_fmaf(es, m, h2);
    unsigned hw_; asm("v_cvt_pk_bf16_f32 %0, %1, %2" : "=v"(hw_) : "v"(outv), "v"(outv));
    float lr_ = outv - __uint_as_float(hw_ << 16);
    unsigned lw_; asm("v_cvt_pk_bf16_f32 %0, %1, %2" : "=v"(lw_) : "v"(lr_), "v"(lr_));
    if (jm2 >= s0){ pch[jm2*64] = (ushort)hw_; pcl[jm2*64] = (ushort)lw_; }
  };

  // ---- prologue: emb group0 -> w_, group1 -> nw_, ids group2 -> qn ----
  {
    i32x4 q0v = *(const i32x4*)(idb + sw);
#pragma unroll
    for (int k=0;k<4;++k){ w_[k] = emb[q0v[k]*64 + d]; b_[k] = emb[q0v[k]*64 + 32 + d]; }
  }
  {
    i32x4 q1v = *(const i32x4*)(idb + clampi(sw + 4));
#pragma unroll
    for (int k=0;k<4;++k){ nw_[k] = emb[q1v[k]*64 + d]; nb_[k] = emb[q1v[k]*64 + 32 + d]; }
  }
  i32x4 qn = *(const i32x4*)(idb + clampi(sw + 8));

  // pipeline fill: body(sw), body(sw+1)
  AF(sw,   w_[0], b_[0]); AB();
  AF(sw+1, w_[1], b_[1]); G0(); AB(); G1();

  // main: bodies j = sw+2 .. send-1 in quads of phases {2,3,0,1}; boundary at phase 0
  for (int i = 0; i < nq-1; ++i){
    int j0 = sw + 2 + 4*i;
    AF(j0,   w_[2], b_[2]); G2(j0-2); G0(); AB(); G1();
    AF(j0+1, w_[3], b_[3]); G2(j0-1); G0(); AB(); G1();
    // group boundary: rotate emb ring, issue next group's loads
#pragma unroll
    for (int k=0;k<4;++k){ w_[k] = nw_[k]; b_[k] = nb_[k]; }
    {
      i32x4 qq = qn;
#pragma unroll
      for (int k=0;k<4;++k){ nw_[k] = emb[qq[k]*64 + d]; nb_[k] = emb[qq[k]*64 + 32 + d]; }
      qn = *(const i32x4*)(idb + clampi(sw + 4*(i+3)));
    }
    AF(j0+2, w_[0], b_[0]); G2(j0);   G0(); AB(); G1();
    AF(j0+3, w_[1], b_[1]); G2(j0+1); G0(); AB(); G1();
  }
  // tail bodies: phases 2,3 of last group
  AF(send-2, w_[2], b_[2]); G2(send-4); G0(); AB(); G1();
  AF(send-1, w_[3], b_[3]); G2(send-3); G0(); AB(); G1();
  // drain
  G2(send-2);
  G0(); G1();
  h2 = h1;
  G2(send-1);
}

// ---------------- projection: [32768,64] x [4096,64]^T, split-bf16 MFMA ----------------
// Changes vs validated R9 gemm: (1) lo.lo pass dropped (error <= 2e-4); (2) epilogue via
// per-wave LDS [64][68] f32 transpose -> global_store_dwordx4 (4x256B segments/instr vs
// 4x64B scalar stores — G13 applied to the output side).
__global__ __launch_bounds__(256) void gemm_kernel(
    const ushort* __restrict__ chi, const ushort* __restrict__ clo,
    const ushort* __restrict__ whi, const ushort* __restrict__ wlo,
    const float* __restrict__ bout, float* __restrict__ out)
{
  __shared__ char lds[69632];  // staging: 4x16KB ; epilogue: 4 waves x 64x68 f32 (17408B)
  const int row0 = blockIdx.y * 128;
  const int v0   = blockIdx.x * 128;
  const int t = threadIdx.x;

  {
    const char* s0 = (const char*)(chi) + (size_t)row0 * 128;
    const char* s1 = (const char*)(clo) + (size_t)row0 * 128;
    const char* s2 = (const char*)(whi) + (size_t)v0 * 128;
    const char* s3 = (const char*)(wlo) + (size_t)v0 * 128;
    const char* srcs[4] = {s0, s1, s2, s3};
#pragma unroll
    for (int a2 = 0; a2 < 4; ++a2){
      char* dst = lds + a2 * 16384;
      const char* src = srcs[a2];
#pragma unroll
      for (int i = 0; i < 4; ++i){
        int id = t + 256 * i;          // 1024 chunks of 16B
        int r = id >> 3, ccol = id & 7;
        i32x4 vv = *(const i32x4*)(src + r*128 + ccol*16);
        *(i32x4*)(dst + r*128 + ((ccol ^ (r & 7)) * 16)) = vv;
      }
    }
  }
  __syncthreads();

  const int lane = t & 63;
  const int wid  = t >> 6;
  const int wr = (wid >> 1) * 64;
  const int wc = (wid & 1) * 64;
  const int lr = lane & 15;
  const int lk = lane >> 4;           // k-group 0..3

  f32x4 acc[4][4];
#pragma unroll
  for (int m = 0; m < 4; ++m)
#pragma unroll
    for (int n = 0; n < 4; ++n) acc[m][n] = (f32x4){0.f, 0.f, 0.f, 0.f};

  i32x2 afr[2][4][4];
#pragma unroll
  for (int hf = 0; hf < 2; ++hf){
    const char* Ab = lds + hf * 16384;
#pragma unroll
    for (int m = 0; m < 4; ++m){
      int row = wr + m*16 + lr;
      const char* rp = Ab + row * 128;
      int sw = (row & 7) << 1;
#pragma unroll
      for (int ks = 0; ks < 4; ++ks){
        int c8 = (ks*4 + lk) ^ sw;
        afr[hf][m][ks] = *(const i32x2*)(rp + c8 * 8);
      }
    }
  }
#pragma unroll
  for (int wh = 0; wh < 2; ++wh){
    const char* Bb = lds + 32768 + wh * 16384;
    i32x2 bfr[4][4];
#pragma unroll
    for (int n = 0; n < 4; ++n){
      int row = wc + n*16 + lr;
      const char* rp = Bb + row * 128;
      int sw = (row & 7) << 1;
#pragma unroll
      for (int ks = 0; ks < 4; ++ks){
        int c8 = (ks*4 + lk) ^ sw;
        bfr[n][ks] = *(const i32x2*)(rp + c8 * 8);
      }
    }
#pragma unroll
    for (int hf = 0; hf < 2; ++hf){
      if (wh == 1 && hf == 1) continue;   // drop lo*lo term (<=2e-4)
#pragma unroll
      for (int m = 0; m < 4; ++m)
#pragma unroll
        for (int n = 0; n < 4; ++n)
#pragma unroll
          for (int ks = 0; ks < 4; ++ks)
            asm("v_mfma_f32_16x16x16_bf16 %0, %1, %2, %0"
                : "+v"(acc[m][n]) : "v"(afr[hf][m][ks]), "v"(bfr[n][ks]));
    }
  }

  // ---- epilogue: per-wave LDS transpose -> vectorized stores ----
  __syncthreads();   // all waves done reading staging LDS
  float* lw = (float*)(lds) + wid * (64*68);
#pragma unroll
  for (int m = 0; m < 4; ++m)
#pragma unroll
    for (int n = 0; n < 4; ++n)
#pragma unroll
      for (int rg = 0; rg < 4; ++rg)
        lw[(m*16 + lk*4 + rg)*68 + n*16 + lr] = acc[m][n][rg];

  const int c4 = lane & 15;           // col quad 0..15
  const int r4 = lane >> 4;           // row-in-group 0..3
  f32x4 bv = *(const f32x4*)(bout + v0 + wc + c4*4);
  float* ob = out + (size_t)(row0 + wr + r4) * 4096 + v0 + wc + c4*4;
#pragma unroll
  for (int it = 0; it < 16; ++it){
    int rr = it*4 + r4;
    f32x4 v = *(const f32x4*)(lw + rr*68 + c4*4);
    v += bv;
    *(f32x4*)(ob + (size_t)(it*4) * 4096) = v;
  }
}

extern "C" void kernel_launch(void* const* d_in, const int* in_sizes, int n_in,
                              void* d_out, int out_size, void* d_ws, size_t ws_size,
                              hipStream_t stream)
{
  const int*   ids  = (const int*)  d_in[0];
  const float* emb  = (const float*)d_in[1];
  const float* Wout = (const float*)d_in[2];
  const float* bout = (const float*)d_in[3];
  const float* Wg   = (const float*)d_in[4];
  const float* bg   = (const float*)d_in[5];
  const float* dlg  = (const float*)d_in[6];
  const float* esc  = (const float*)d_in[7];
  float* out = (float*)d_out;
  char* ws = (char*)d_ws;
  // ws layout: c_hi 4MB | c_lo 4MB | w_hi 512KB | w_lo 512KB  (9MB total)
  ushort* chi = (ushort*)(ws);
  ushort* clo = (ushort*)(ws + 4u*1024u*1024u);
  ushort* whi = (ushort*)(ws + 8u*1024u*1024u);
  ushort* wlo = (ushort*)(ws + 8u*1024u*1024u + 512u*1024u);

  // blocks 0..1023: scan (64 chunks x 16 batches); 1024..2047: W split (k''-permuted)
  scan_kernel<<<dim3(2048), dim3(64), 0, stream>>>(ids, emb, Wg, bg, dlg, esc,
                                                   chi, clo, Wout, whi, wlo);
  gemm_kernel<<<dim3(32, 256), dim3(256), 0, stream>>>(chi, clo, whi, wlo, bout, out);
}

// Round 12
// 156.593 us; speedup vs baseline: 1.1228x; 1.1228x over previous
//
#include <hip/hip_runtime.h>

#define S_LEN 2048

typedef float f32x4 __attribute__((ext_vector_type(4)));
typedef int   i32x4 __attribute__((ext_vector_type(4)));
typedef int   i32x2 __attribute__((ext_vector_type(2)));

__device__ __forceinline__ float cos2pi(float rev){ float r; asm("v_cos_f32 %0, %1":"=v"(r):"v"(rev)); return r; }
__device__ __forceinline__ float fractf_(float x){ float r; asm("v_fract_f32 %0, %1":"=v"(r):"v"(x)); return r; }
template<int M>
__device__ __forceinline__ float swz(float x){
  return __int_as_float(__builtin_amdgcn_ds_swizzle(__float_as_int(x), M));
}
template<int CTRL>
__device__ __forceinline__ float dppmov(float x){
  return __int_as_float(__builtin_amdgcn_update_dpp(0, __float_as_int(x), CTRL, 0xf, 0xf, false));
}

// lane layout (scan): comp = l>>5 (0:h_r, 1:h_i), d = ((l>>2)&7) | ((l&3)<<3) => head(d) = l&3
// K-permutation: comb element k'' = l  <->  concat index comp*32 + d. W columns permuted identically.

// ================= scan (blocks 0..1023) + W-split prep (blocks 1024..2047) =================
// 64 chunks x 32 steps, 128-step warm-up (validated WU; R8 proved 96 insufficient).
// Body/numerics bit-identical to R9/R11. 3-stage pipeline:
//   AF(j) theta->rev, issue shfl | G2(j-2) | G0(j-1) folds, issue swizzle | AB(j) | G1(j-1)
__global__ __launch_bounds__(64) void scan_kernel(
    const int* __restrict__ ids, const float* __restrict__ emb,
    const float* __restrict__ Wg, const float* __restrict__ bg,
    const float* __restrict__ dlg, const float* __restrict__ esc,
    ushort* __restrict__ chi, ushort* __restrict__ clo,
    const float* __restrict__ W32, ushort* __restrict__ whi, ushort* __restrict__ wlo)
{
  const int w = blockIdx.x;
  const int l = threadIdx.x;

  if (w >= 1024){
    // ---- W_out -> bf16 hi/lo split with k'' lane permutation (validated R7/R9) ----
    int i0 = (w - 1024) * 256 + l * 4;
    int v  = i0 >> 6;
    int q  = (i0 & 63) >> 2;
    int base = v*64 + (q >> 3)*32 + (q & 7);
    float x0 = W32[base], x1 = W32[base+8], x2 = W32[base+16], x3 = W32[base+24];
    unsigned hw01, hw23, lw01, lw23;
    asm("v_cvt_pk_bf16_f32 %0, %1, %2":"=v"(hw01):"v"(x0),"v"(x1));
    asm("v_cvt_pk_bf16_f32 %0, %1, %2":"=v"(hw23):"v"(x2),"v"(x3));
    float r0 = x0 - __uint_as_float(hw01 << 16);
    float r1 = x1 - __uint_as_float(hw01 & 0xffff0000u);
    float r2 = x2 - __uint_as_float(hw23 << 16);
    float r3 = x3 - __uint_as_float(hw23 & 0xffff0000u);
    asm("v_cvt_pk_bf16_f32 %0, %1, %2":"=v"(lw01):"v"(r0),"v"(r1));
    asm("v_cvt_pk_bf16_f32 %0, %1, %2":"=v"(lw23):"v"(r2),"v"(r3));
    *(i32x2*)(whi + i0) = (i32x2){(int)hw01, (int)hw23};
    *(i32x2*)(wlo + i0) = (i32x2){(int)lw01, (int)lw23};
    return;
  }

  const int c  = w >> 4;            // chunk 0..63
  const int b  = w & 15;            // batch
  const bool lo = (l < 32);
  const int d  = ((l >> 2) & 7) | ((l & 3) << 3);
  const bool b0 = (l & 1) != 0;
  const bool b1 = (l & 2) != 0;
  const float qoff = lo ? 0.f : 0.25f;   // cos(x - 1/4 rev) = sin(x)

  const float es  = esc[0];
  const int hd = l & 3;
  const float dk  = 1.f/(1.f + __expf(-dlg[hd]));
  const float bgl = bg[hd];
  const int crow = (lo ? 0 : 32) + d;
  const f32x4 wg = *(const f32x4*)(Wg + crow*4);

  const int s0   = c*32;
  const int sw   = (s0 >= 128) ? (s0 - 128) : 0;
  const int send = s0 + 32;
  const int nq   = (send - sw) >> 2;   // 8..40 four-step groups

  const int* idb = ids + b*S_LEN;
  ushort* pch = chi + (size_t)b*S_LEN*64 + l;
  ushort* pcl = clo + (size_t)b*S_LEN*64 + l;

  const float PHI_F   = 1.6180339887498949f;
  const float TWOPI_F = 6.283185307179586f;
  const float INV2PI  = 0.15915494309189535f;

  float h = 0.f, m = 0.f;
  float h1 = 0.f, h2 = 0.f;     // h(j-1), h(j-2)
  float rev_c, rev_s;           // A pipeline (step j)
  float q0p, swp;               // G0 -> G1 (step j-1)
  float mm1p, psp;              // G1 -> G2 (step j-2)
  float w_[4], b_[4], nw_[4], nb_[4];

  auto clampi = [](int x){ return x > (S_LEN-4) ? (S_LEN-4) : x; };

  auto AF = [&](int s, float wv, float bpv){
    float invw = __builtin_amdgcn_rcpf(1.f + __builtin_fabsf(wv));
    float tp = (float)s * PHI_F;
    float th = __builtin_fmaf(h, invw, bpv) + tp;   // R3-exact order
    float qf = __builtin_floorf(th * INV2PI);
    float r  = __builtin_fmaf(-qf, TWOPI_F, th);
    r = (r < 0.f) ? (r + TWOPI_F) : r;
    r = (r >= TWOPI_F) ? (r - TWOPI_F) : r;
    rev_c = r * INV2PI;                              // [0,1)
    rev_s = __shfl_xor(rev_c, 32, 64);               // issue ds op; consume in AB
  };
  auto AB = [&](){
    float rsum = rev_c + rev_s;                      // identical rounding both halves
    float hn = cos2pi(fractf_(rsum - qoff));         // h_r=cos, h_i=sin via -1/4 rev
    h2 = h1; h1 = hn; h = hn;
  };
  auto G0 = [&](){
    float p0 = h1*wg[0], p1 = h1*wg[1], p2 = h1*wg[2], p3 = h1*wg[3];
    float m01 = b0 ? p1 : p0;
    float t01 = b0 ? p0 : p1;
    m01 += dppmov<0xB1>(t01);              // quad_perm xor1
    float m23 = b0 ? p3 : p2;
    float t23 = b0 ? p2 : p3;
    m23 += dppmov<0xB1>(t23);
    float mm = b1 ? m23 : m01;
    float tt = b1 ? m01 : m23;
    mm += dppmov<0x4E>(tt);                // quad_perm xor2
    mm += dppmov<0x124>(mm);               // row_ror:4
    mm += dppmov<0x128>(mm);               // row_ror:8
    q0p = mm;
    swp = swz<0x401F>(mm);                 // issue ds op; consume in G1
  };
  auto G1 = [&](){
    float mm1 = q0p + swp;
    mm1p = mm1;
    psp = __shfl_xor(mm1, 32, 64);         // issue ds op; consume next body's G2
  };
  auto G2 = [&](int jm2){
    float mm = mm1p + psp;                 // full 64-lane sum, all lanes
    float g_ = 1.f / (1.f + __expf(-(mm + bgl)));
    m = __builtin_fmaf(dk, m, g_*h2);
    float outv = __builtin_fmaf(es, m, h2);
    unsigned hw_; asm("v_cvt_pk_bf16_f32 %0, %1, %2" : "=v"(hw_) : "v"(outv), "v"(outv));
    float lr_ = outv - __uint_as_float(hw_ << 16);
    unsigned lw_; asm("v_cvt_pk_bf16_f32 %0, %1, %2" : "=v"(lw_) : "v"(lr_), "v"(lr_));
    if (jm2 >= s0){ pch[jm2*64] = (ushort)hw_; pcl[jm2*64] = (ushort)lw_; }
  };

  // ---- prologue: emb group0 -> w_, group1 -> nw_, ids group2 -> qn ----
  {
    i32x4 q0v = *(const i32x4*)(idb + sw);
#pragma unroll
    for (int k=0;k<4;++k){ w_[k] = emb[q0v[k]*64 + d]; b_[k] = emb[q0v[k]*64 + 32 + d]; }
  }
  {
    i32x4 q1v = *(const i32x4*)(idb + clampi(sw + 4));
#pragma unroll
    for (int k=0;k<4;++k){ nw_[k] = emb[q1v[k]*64 + d]; nb_[k] = emb[q1v[k]*64 + 32 + d]; }
  }
  i32x4 qn = *(const i32x4*)(idb + clampi(sw + 8));

  // pipeline fill: body(sw), body(sw+1)
  AF(sw,   w_[0], b_[0]); AB();
  AF(sw+1, w_[1], b_[1]); G0(); AB(); G1();

  // main: bodies j = sw+2 .. send-1 in quads of phases {2,3,0,1}; boundary at phase 0
  for (int i = 0; i < nq-1; ++i){
    int j0 = sw + 2 + 4*i;
    AF(j0,   w_[2], b_[2]); G2(j0-2); G0(); AB(); G1();
    AF(j0+1, w_[3], b_[3]); G2(j0-1); G0(); AB(); G1();
    // group boundary: rotate emb ring, issue next group's loads
#pragma unroll
    for (int k=0;k<4;++k){ w_[k] = nw_[k]; b_[k] = nb_[k]; }
    {
      i32x4 qq = qn;
#pragma unroll
      for (int k=0;k<4;++k){ nw_[k] = emb[qq[k]*64 + d]; nb_[k] = emb[qq[k]*64 + 32 + d]; }
      qn = *(const i32x4*)(idb + clampi(sw + 4*(i+3)));
    }
    AF(j0+2, w_[0], b_[0]); G2(j0);   G0(); AB(); G1();
    AF(j0+3, w_[1], b_[1]); G2(j0+1); G0(); AB(); G1();
  }
  // tail bodies: phases 2,3 of last group
  AF(send-2, w_[2], b_[2]); G2(send-4); G0(); AB(); G1();
  AF(send-1, w_[3], b_[3]); G2(send-3); G0(); AB(); G1();
  // drain
  G2(send-2);
  G0(); G1();
  h2 = h1;
  G2(send-1);
}

// ---------------- projection: [32768,64] x [4096,64]^T, split-bf16 MFMA ----------------
// R9's validated direct-store epilogue restored (R11's LDS-transpose epilogue regressed
// ~+17 µs: extra barrier + LDS round-trip against stores that were already near-roofline).
// lo*lo pass drop kept (validated R11, absmax unchanged).
__global__ __launch_bounds__(256) void gemm_kernel(
    const ushort* __restrict__ chi, const ushort* __restrict__ clo,
    const ushort* __restrict__ whi, const ushort* __restrict__ wlo,
    const float* __restrict__ bout, float* __restrict__ out)
{
  __shared__ char lds[65536];  // A_hi | A_lo | W_hi | W_lo, 16KB each
  const int row0 = blockIdx.y * 128;
  const int v0   = blockIdx.x * 128;
  const int t = threadIdx.x;

  {
    const char* s0 = (const char*)(chi) + (size_t)row0 * 128;
    const char* s1 = (const char*)(clo) + (size_t)row0 * 128;
    const char* s2 = (const char*)(whi) + (size_t)v0 * 128;
    const char* s3 = (const char*)(wlo) + (size_t)v0 * 128;
    const char* srcs[4] = {s0, s1, s2, s3};
#pragma unroll
    for (int a2 = 0; a2 < 4; ++a2){
      char* dst = lds + a2 * 16384;
      const char* src = srcs[a2];
#pragma unroll
      for (int i = 0; i < 4; ++i){
        int id = t + 256 * i;          // 1024 chunks of 16B
        int r = id >> 3, ccol = id & 7;
        i32x4 vv = *(const i32x4*)(src + r*128 + ccol*16);
        *(i32x4*)(dst + r*128 + ((ccol ^ (r & 7)) * 16)) = vv;
      }
    }
  }
  __syncthreads();

  const int lane = t & 63;
  const int wid  = t >> 6;
  const int wr = (wid >> 1) * 64;
  const int wc = (wid & 1) * 64;
  const int lr = lane & 15;
  const int lk = lane >> 4;           // k-group 0..3

  f32x4 acc[4][4];
#pragma unroll
  for (int m = 0; m < 4; ++m)
#pragma unroll
    for (int n = 0; n < 4; ++n) acc[m][n] = (f32x4){0.f, 0.f, 0.f, 0.f};

  i32x2 afr[2][4][4];
#pragma unroll
  for (int hf = 0; hf < 2; ++hf){
    const char* Ab = lds + hf * 16384;
#pragma unroll
    for (int m = 0; m < 4; ++m){
      int row = wr + m*16 + lr;
      const char* rp = Ab + row * 128;
      int sw = (row & 7) << 1;
#pragma unroll
      for (int ks = 0; ks < 4; ++ks){
        int c8 = (ks*4 + lk) ^ sw;
        afr[hf][m][ks] = *(const i32x2*)(rp + c8 * 8);
      }
    }
  }
#pragma unroll
  for (int wh = 0; wh < 2; ++wh){
    const char* Bb = lds + 32768 + wh * 16384;
    i32x2 bfr[4][4];
#pragma unroll
    for (int n = 0; n < 4; ++n){
      int row = wc + n*16 + lr;
      const char* rp = Bb + row * 128;
      int sw = (row & 7) << 1;
#pragma unroll
      for (int ks = 0; ks < 4; ++ks){
        int c8 = (ks*4 + lk) ^ sw;
        bfr[n][ks] = *(const i32x2*)(rp + c8 * 8);
      }
    }
#pragma unroll
    for (int hf = 0; hf < 2; ++hf){
      if (wh == 1 && hf == 1) continue;   // drop lo*lo term (<=2e-4, validated R11)
#pragma unroll
      for (int m = 0; m < 4; ++m)
#pragma unroll
        for (int n = 0; n < 4; ++n)
#pragma unroll
          for (int ks = 0; ks < 4; ++ks)
            asm("v_mfma_f32_16x16x16_bf16 %0, %1, %2, %0"
                : "+v"(acc[m][n]) : "v"(afr[hf][m][ks]), "v"(bfr[n][ks]));
    }
  }

  // epilogue (R9-validated): C/D layout col = lane&15, row = (lane>>4)*4 + reg
#pragma unroll
  for (int n = 0; n < 4; ++n){
    float bias = bout[v0 + wc + n*16 + lr];
#pragma unroll
    for (int m = 0; m < 4; ++m){
      int gr = row0 + wr + m*16 + lk*4;
      float* op = out + (size_t)gr * 4096 + (v0 + wc + n*16 + lr);
#pragma unroll
      for (int rg = 0; rg < 4; ++rg){
        op[(size_t)rg * 4096] = acc[m][n][rg] + bias;
      }
    }
  }
}

extern "C" void kernel_launch(void* const* d_in, const int* in_sizes, int n_in,
                              void* d_out, int out_size, void* d_ws, size_t ws_size,
                              hipStream_t stream)
{
  const int*   ids  = (const int*)  d_in[0];
  const float* emb  = (const float*)d_in[1];
  const float* Wout = (const float*)d_in[2];
  const float* bout = (const float*)d_in[3];
  const float* Wg   = (const float*)d_in[4];
  const float* bg   = (const float*)d_in[5];
  const float* dlg  = (const float*)d_in[6];
  const float* esc  = (const float*)d_in[7];
  float* out = (float*)d_out;
  char* ws = (char*)d_ws;
  // ws layout: c_hi 4MB | c_lo 4MB | w_hi 512KB | w_lo 512KB  (9MB total)
  ushort* chi = (ushort*)(ws);
  ushort* clo = (ushort*)(ws + 4u*1024u*1024u);
  ushort* whi = (ushort*)(ws + 8u*1024u*1024u);
  ushort* wlo = (ushort*)(ws + 8u*1024u*1024u + 512u*1024u);

  // blocks 0..1023: scan (64 chunks x 16 batches); 1024..2047: W split (k''-permuted)
  scan_kernel<<<dim3(2048), dim3(64), 0, stream>>>(ids, emb, Wg, bg, dlg, esc,
                                                   chi, clo, Wout, whi, wlo);
  gemm_kernel<<<dim3(32, 256), dim3(256), 0, stream>>>(chi, clo, whi, wlo, bout, out);
}

// Round 13
// 149.816 us; speedup vs baseline: 1.1735x; 1.0452x over previous
//
#include <hip/hip_runtime.h>

#define S_LEN 2048

typedef float f32x4 __attribute__((ext_vector_type(4)));
typedef int   i32x4 __attribute__((ext_vector_type(4)));
typedef int   i32x2 __attribute__((ext_vector_type(2)));

__device__ __forceinline__ float sin2pi(float rev){ float r; asm("v_sin_f32 %0, %1":"=v"(r):"v"(rev)); return r; }
__device__ __forceinline__ float cos2pi(float rev){ float r; asm("v_cos_f32 %0, %1":"=v"(r):"v"(rev)); return r; }
__device__ __forceinline__ float fractf_(float x){ float r; asm("v_fract_f32 %0, %1":"=v"(r):"v"(x)); return r; }
template<int M>
__device__ __forceinline__ float swz(float x){
  return __int_as_float(__builtin_amdgcn_ds_swizzle(__float_as_int(x), M));
}
template<int CTRL>
__device__ __forceinline__ float dppmov(float x){
  return __int_as_float(__builtin_amdgcn_update_dpp(0, __float_as_int(x), CTRL, 0xf, 0xf, false));
}

// lane layout (scan full phase): comp = l>>5 (0:h_r, 1:h_i), d = ((l>>2)&7) | ((l&3)<<3)
// => head(d) = l&3. K-perm: comb element k'' = l <-> concat index comp*32 + d.
// h-only warm-up phase: each lane holds BOTH components (hcr,hci) of dim d — pure VALU
// (R10-validated numerics), no cross-lane, no gate, no stores. h is independent of m/gate,
// and m's history >64 steps back decays as dk^64 (<~1e-3 logit impact), so the first 64
// warm-up steps can skip the gate entirely — for speculative AND exact chunks alike.

// ================= scan (blocks 0..1023) + W-split prep (blocks 1024..2047) =================
// 64 chunks x 32 steps. Warm-up: 128 h-steps total (validated class; R8 proved 96 fails),
// of which first 64 are h-only (cheap ~130cy) and last 64 full-body (gate+m, no stores).
__global__ __launch_bounds__(64) void scan_kernel(
    const int* __restrict__ ids, const float* __restrict__ emb,
    const float* __restrict__ Wg, const float* __restrict__ bg,
    const float* __restrict__ dlg, const float* __restrict__ esc,
    ushort* __restrict__ chi, ushort* __restrict__ clo,
    const float* __restrict__ W32, ushort* __restrict__ whi, ushort* __restrict__ wlo)
{
  const int w = blockIdx.x;
  const int l = threadIdx.x;

  if (w >= 1024){
    // ---- W_out -> bf16 hi/lo split with k'' lane permutation (validated R7/R9) ----
    int i0 = (w - 1024) * 256 + l * 4;
    int v  = i0 >> 6;
    int q  = (i0 & 63) >> 2;
    int base = v*64 + (q >> 3)*32 + (q & 7);
    float x0 = W32[base], x1 = W32[base+8], x2 = W32[base+16], x3 = W32[base+24];
    unsigned hw01, hw23, lw01, lw23;
    asm("v_cvt_pk_bf16_f32 %0, %1, %2":"=v"(hw01):"v"(x0),"v"(x1));
    asm("v_cvt_pk_bf16_f32 %0, %1, %2":"=v"(hw23):"v"(x2),"v"(x3));
    float r0 = x0 - __uint_as_float(hw01 << 16);
    float r1 = x1 - __uint_as_float(hw01 & 0xffff0000u);
    float r2 = x2 - __uint_as_float(hw23 << 16);
    float r3 = x3 - __uint_as_float(hw23 & 0xffff0000u);
    asm("v_cvt_pk_bf16_f32 %0, %1, %2":"=v"(lw01):"v"(r0),"v"(r1));
    asm("v_cvt_pk_bf16_f32 %0, %1, %2":"=v"(lw23):"v"(r2),"v"(r3));
    *(i32x2*)(whi + i0) = (i32x2){(int)hw01, (int)hw23};
    *(i32x2*)(wlo + i0) = (i32x2){(int)lw01, (int)lw23};
    return;
  }

  const int c  = w >> 4;            // chunk 0..63
  const int b  = w & 15;            // batch
  const bool lo = (l < 32);
  const int d  = ((l >> 2) & 7) | ((l & 3) << 3);   // mirrors for l>=32
  const bool b0 = (l & 1) != 0;
  const bool b1 = (l & 2) != 0;
  const float qoff = lo ? 0.f : 0.25f;   // cos(x - 1/4 rev) = sin(x)

  const float es  = esc[0];
  const int hd = l & 3;
  const float dk  = 1.f/(1.f + __expf(-dlg[hd]));
  const float bgl = bg[hd];
  const int crow = (lo ? 0 : 32) + d;
  const f32x4 wg = *(const f32x4*)(Wg + crow*4);

  const int s0   = c*32;
  const int sw   = (s0 >= 128) ? (s0 - 128) : 0;   // h-warm-up start (128 total h-steps)
  const int f0   = (s0 >= 64)  ? (s0 - 64)  : 0;   // full-body start (64 gate/m warm steps)
  const int send = s0 + 32;
  const int ngH  = (f0 - sw) >> 2;                 // h-only groups: 0, 8, or 16
  const int nq   = (send - f0) >> 2;               // full-body groups: 8..24

  const int* idb = ids + b*S_LEN;
  ushort* pch = chi + (size_t)b*S_LEN*64 + l;
  ushort* pcl = clo + (size_t)b*S_LEN*64 + l;

  const float PHI_F   = 1.6180339887498949f;
  const float TWOPI_F = 6.283185307179586f;
  const float INV2PI  = 0.15915494309189535f;

  float h = 0.f, m = 0.f;

  auto clampi = [](int x){ return x > (S_LEN-4) ? (S_LEN-4) : x; };

  // ================= phase 1: h-only warm-up (dual-component, pure VALU) =================
  if (ngH > 0){
    float hcr = 0.f, hci = 0.f;
    float cw[4], cb[4], cnw[4], cnb[4];
    {
      i32x4 qa = *(const i32x4*)(idb + sw);
#pragma unroll
      for (int k=0;k<4;++k){ cw[k] = emb[qa[k]*64 + d]; cb[k] = emb[qa[k]*64 + 32 + d]; }
      i32x4 qb = *(const i32x4*)(idb + clampi(sw + 4));
#pragma unroll
      for (int k=0;k<4;++k){ cnw[k] = emb[qb[k]*64 + d]; cnb[k] = emb[qb[k]*64 + 32 + d]; }
    }
    i32x4 qc = *(const i32x4*)(idb + clampi(sw + 8));
    for (int g = 0; g < ngH; ++g){
      int sb = sw + 4*g;
#pragma unroll
      for (int k=0;k<4;++k){
        // R10-validated per-theta step (both components in-lane)
        float wv = cw[k], bpv = cb[k];
        float invw = __builtin_amdgcn_rcpf(1.f + __builtin_fabsf(wv));
        float tp = (float)(sb + k) * PHI_F;
        float thr = __builtin_fmaf(hcr, invw, bpv) + tp;
        float thi = __builtin_fmaf(hci, invw, bpv) + tp;
        float qr = __builtin_floorf(thr * INV2PI);
        float rr = __builtin_fmaf(-qr, TWOPI_F, thr);
        rr = (rr < 0.f) ? (rr + TWOPI_F) : rr;
        rr = (rr >= TWOPI_F) ? (rr - TWOPI_F) : rr;
        float qi = __builtin_floorf(thi * INV2PI);
        float ri = __builtin_fmaf(-qi, TWOPI_F, thi);
        ri = (ri < 0.f) ? (ri + TWOPI_F) : ri;
        ri = (ri >= TWOPI_F) ? (ri - TWOPI_F) : ri;
        float sr = sin2pi(rr * INV2PI), cr = cos2pi(rr * INV2PI);
        float si = sin2pi(ri * INV2PI), ci = cos2pi(ri * INV2PI);
        float nhr = __builtin_fmaf(cr, ci, -(sr*si));
        float nhi = __builtin_fmaf(cr, si,  sr*ci);
        hcr = nhr; hci = nhi;
      }
#pragma unroll
      for (int k=0;k<4;++k){ cw[k] = cnw[k]; cb[k] = cnb[k]; }
      {
        i32x4 qq = qc;
#pragma unroll
        for (int k=0;k<4;++k){ cnw[k] = emb[qq[k]*64 + d]; cnb[k] = emb[qq[k]*64 + 32 + d]; }
        qc = *(const i32x4*)(idb + clampi(sw + 4*(g+3)));
      }
    }
    // transition: dual layout -> R9 lane layout (lane l takes comp l>>5 of dim d(l&31))
    float xr = __shfl(hcr, l & 31, 64);
    float xi = __shfl(hci, l & 31, 64);
    h = lo ? xr : xi;
  }

  // ================= phase 2: full body (R12-identical 3-stage pipeline) =================
  float h1 = h, h2 = h;         // latches (overwritten before first real use)
  float rev_c, rev_s;           // A pipeline (step j)
  float q0p, swp;               // G0 -> G1 (step j-1)
  float mm1p, psp;              // G1 -> G2 (step j-2)
  float w_[4], b_[4], nw_[4], nb_[4];

  auto AF = [&](int s, float wv, float bpv){
    float invw = __builtin_amdgcn_rcpf(1.f + __builtin_fabsf(wv));
    float tp = (float)s * PHI_F;
    float th = __builtin_fmaf(h, invw, bpv) + tp;   // R3-exact order
    float qf = __builtin_floorf(th * INV2PI);
    float r  = __builtin_fmaf(-qf, TWOPI_F, th);
    r = (r < 0.f) ? (r + TWOPI_F) : r;
    r = (r >= TWOPI_F) ? (r - TWOPI_F) : r;
    rev_c = r * INV2PI;                              // [0,1)
    rev_s = __shfl_xor(rev_c, 32, 64);               // issue ds op; consume in AB
  };
  auto AB = [&](){
    float rsum = rev_c + rev_s;                      // identical rounding both halves
    float hn = cos2pi(fractf_(rsum - qoff));         // h_r=cos, h_i=sin via -1/4 rev
    h2 = h1; h1 = hn; h = hn;
  };
  auto G0 = [&](){
    float p0 = h1*wg[0], p1 = h1*wg[1], p2 = h1*wg[2], p3 = h1*wg[3];
    float m01 = b0 ? p1 : p0;
    float t01 = b0 ? p0 : p1;
    m01 += dppmov<0xB1>(t01);              // quad_perm xor1
    float m23 = b0 ? p3 : p2;
    float t23 = b0 ? p2 : p3;
    m23 += dppmov<0xB1>(t23);
    float mm = b1 ? m23 : m01;
    float tt = b1 ? m01 : m23;
    mm += dppmov<0x4E>(tt);                // quad_perm xor2
    mm += dppmov<0x124>(mm);               // row_ror:4
    mm += dppmov<0x128>(mm);               // row_ror:8
    q0p = mm;
    swp = swz<0x401F>(mm);                 // issue ds op; consume in G1
  };
  auto G1 = [&](){
    float mm1 = q0p + swp;
    mm1p = mm1;
    psp = __shfl_xor(mm1, 32, 64);         // issue ds op; consume next body's G2
  };
  auto G2 = [&](int jm2){
    float mm = mm1p + psp;                 // full 64-lane sum, all lanes
    float g_ = 1.f / (1.f + __expf(-(mm + bgl)));
    m = __builtin_fmaf(dk, m, g_*h2);
    float outv = __builtin_fmaf(es, m, h2);
    unsigned hw_; asm("v_cvt_pk_bf16_f32 %0, %1, %2" : "=v"(hw_) : "v"(outv), "v"(outv));
    float lr_ = outv - __uint_as_float(hw_ << 16);
    unsigned lw_; asm("v_cvt_pk_bf16_f32 %0, %1, %2" : "=v"(lw_) : "v"(lr_), "v"(lr_));
    if (jm2 >= s0){ pch[jm2*64] = (ushort)hw_; pcl[jm2*64] = (ushort)lw_; }
  };

  // ---- prologue: emb group0 -> w_, group1 -> nw_, ids group2 -> qn (from f0) ----
  {
    i32x4 q0v = *(const i32x4*)(idb + f0);
#pragma unroll
    for (int k=0;k<4;++k){ w_[k] = emb[q0v[k]*64 + d]; b_[k] = emb[q0v[k]*64 + 32 + d]; }
  }
  {
    i32x4 q1v = *(const i32x4*)(idb + clampi(f0 + 4));
#pragma unroll
    for (int k=0;k<4;++k){ nw_[k] = emb[q1v[k]*64 + d]; nb_[k] = emb[q1v[k]*64 + 32 + d]; }
  }
  i32x4 qn = *(const i32x4*)(idb + clampi(f0 + 8));

  // pipeline fill: body(f0), body(f0+1)
  AF(f0,   w_[0], b_[0]); AB();
  AF(f0+1, w_[1], b_[1]); G0(); AB(); G1();

  // main: bodies j = f0+2 .. send-1 in quads of phases {2,3,0,1}; boundary at phase 0
  for (int i = 0; i < nq-1; ++i){
    int j0 = f0 + 2 + 4*i;
    AF(j0,   w_[2], b_[2]); G2(j0-2); G0(); AB(); G1();
    AF(j0+1, w_[3], b_[3]); G2(j0-1); G0(); AB(); G1();
    // group boundary: rotate emb ring, issue next group's loads
#pragma unroll
    for (int k=0;k<4;++k){ w_[k] = nw_[k]; b_[k] = nb_[k]; }
    {
      i32x4 qq = qn;
#pragma unroll
      for (int k=0;k<4;++k){ nw_[k] = emb[qq[k]*64 + d]; nb_[k] = emb[qq[k]*64 + 32 + d]; }
      qn = *(const i32x4*)(idb + clampi(f0 + 4*(i+3)));
    }
    AF(j0+2, w_[0], b_[0]); G2(j0);   G0(); AB(); G1();
    AF(j0+3, w_[1], b_[1]); G2(j0+1); G0(); AB(); G1();
  }
  // tail bodies: phases 2,3 of last group
  AF(send-2, w_[2], b_[2]); G2(send-4); G0(); AB(); G1();
  AF(send-1, w_[3], b_[3]); G2(send-3); G0(); AB(); G1();
  // drain
  G2(send-2);
  G0(); G1();
  h2 = h1;
  G2(send-1);
}

// ---------------- projection: [32768,64] x [4096,64]^T, split-bf16 MFMA (R12-identical) ----------------
__global__ __launch_bounds__(256) void gemm_kernel(
    const ushort* __restrict__ chi, const ushort* __restrict__ clo,
    const ushort* __restrict__ whi, const ushort* __restrict__ wlo,
    const float* __restrict__ bout, float* __restrict__ out)
{
  __shared__ char lds[65536];  // A_hi | A_lo | W_hi | W_lo, 16KB each
  const int row0 = blockIdx.y * 128;
  const int v0   = blockIdx.x * 128;
  const int t = threadIdx.x;

  {
    const char* s0 = (const char*)(chi) + (size_t)row0 * 128;
    const char* s1 = (const char*)(clo) + (size_t)row0 * 128;
    const char* s2 = (const char*)(whi) + (size_t)v0 * 128;
    const char* s3 = (const char*)(wlo) + (size_t)v0 * 128;
    const char* srcs[4] = {s0, s1, s2, s3};
#pragma unroll
    for (int a2 = 0; a2 < 4; ++a2){
      char* dst = lds + a2 * 16384;
      const char* src = srcs[a2];
#pragma unroll
      for (int i = 0; i < 4; ++i){
        int id = t + 256 * i;          // 1024 chunks of 16B
        int r = id >> 3, ccol = id & 7;
        i32x4 vv = *(const i32x4*)(src + r*128 + ccol*16);
        *(i32x4*)(dst + r*128 + ((ccol ^ (r & 7)) * 16)) = vv;
      }
    }
  }
  __syncthreads();

  const int lane = t & 63;
  const int wid  = t >> 6;
  const int wr = (wid >> 1) * 64;
  const int wc = (wid & 1) * 64;
  const int lr = lane & 15;
  const int lk = lane >> 4;           // k-group 0..3

  f32x4 acc[4][4];
#pragma unroll
  for (int m = 0; m < 4; ++m)
#pragma unroll
    for (int n = 0; n < 4; ++n) acc[m][n] = (f32x4){0.f, 0.f, 0.f, 0.f};

  i32x2 afr[2][4][4];
#pragma unroll
  for (int hf = 0; hf < 2; ++hf){
    const char* Ab = lds + hf * 16384;
#pragma unroll
    for (int m = 0; m < 4; ++m){
      int row = wr + m*16 + lr;
      const char* rp = Ab + row * 128;
      int sw = (row & 7) << 1;
#pragma unroll
      for (int ks = 0; ks < 4; ++ks){
        int c8 = (ks*4 + lk) ^ sw;
        afr[hf][m][ks] = *(const i32x2*)(rp + c8 * 8);
      }
    }
  }
#pragma unroll
  for (int wh = 0; wh < 2; ++wh){
    const char* Bb = lds + 32768 + wh * 16384;
    i32x2 bfr[4][4];
#pragma unroll
    for (int n = 0; n < 4; ++n){
      int row = wc + n*16 + lr;
      const char* rp = Bb + row * 128;
      int sw = (row & 7) << 1;
#pragma unroll
      for (int ks = 0; ks < 4; ++ks){
        int c8 = (ks*4 + lk) ^ sw;
        bfr[n][ks] = *(const i32x2*)(rp + c8 * 8);
      }
    }
#pragma unroll
    for (int hf = 0; hf < 2; ++hf){
      if (wh == 1 && hf == 1) continue;   // drop lo*lo term (<=2e-4, validated R11)
#pragma unroll
      for (int m = 0; m < 4; ++m)
#pragma unroll
        for (int n = 0; n < 4; ++n)
#pragma unroll
          for (int ks = 0; ks < 4; ++ks)
            asm("v_mfma_f32_16x16x16_bf16 %0, %1, %2, %0"
                : "+v"(acc[m][n]) : "v"(afr[hf][m][ks]), "v"(bfr[n][ks]));
    }
  }

  // epilogue (R9-validated): C/D layout col = lane&15, row = (lane>>4)*4 + reg
#pragma unroll
  for (int n = 0; n < 4; ++n){
    float bias = bout[v0 + wc + n*16 + lr];
#pragma unroll
    for (int m = 0; m < 4; ++m){
      int gr = row0 + wr + m*16 + lk*4;
      float* op = out + (size_t)gr * 4096 + (v0 + wc + n*16 + lr);
#pragma unroll
      for (int rg = 0; rg < 4; ++rg){
        op[(size_t)rg * 4096] = acc[m][n][rg] + bias;
      }
    }
  }
}

extern "C" void kernel_launch(void* const* d_in, const int* in_sizes, int n_in,
                              void* d_out, int out_size, void* d_ws, size_t ws_size,
                              hipStream_t stream)
{
  const int*   ids  = (const int*)  d_in[0];
  const float* emb  = (const float*)d_in[1];
  const float* Wout = (const float*)d_in[2];
  const float* bout = (const float*)d_in[3];
  const float* Wg   = (const float*)d_in[4];
  const float* bg   = (const float*)d_in[5];
  const float* dlg  = (const float*)d_in[6];
  const float* esc  = (const float*)d_in[7];
  float* out = (float*)d_out;
  char* ws = (char*)d_ws;
  // ws layout: c_hi 4MB | c_lo 4MB | w_hi 512KB | w_lo 512KB  (9MB total)
  ushort* chi = (ushort*)(ws);
  ushort* clo = (ushort*)(ws + 4u*1024u*1024u);
  ushort* whi = (ushort*)(ws + 8u*1024u*1024u);
  ushort* wlo = (ushort*)(ws + 8u*1024u*1024u + 512u*1024u);

  // blocks 0..1023: scan (64 chunks x 16 batches); 1024..2047: W split (k''-permuted)
  scan_kernel<<<dim3(2048), dim3(64), 0, stream>>>(ids, emb, Wg, bg, dlg, esc,
                                                   chi, clo, Wout, whi, wlo);
  gemm_kernel<<<dim3(32, 256), dim3(256), 0, stream>>>(chi, clo, whi, wlo, bout, out);
}